// Round 5
// baseline (519.514 us; speedup 1.0000x reference)
//
#include <hip/hip_runtime.h>
#include <math.h>

#define NB 4
#define C_ 256
#define NG 8
#define CPG 32
#define HW 4096
#define NH 4
#define HD 64
#define EPS 1e-5f
#define QSCALE 0.1803368801111204f  /* 0.125 * log2(e): folds 1/sqrt(64) and base-2 softmax */

typedef __attribute__((ext_vector_type(8))) short bf16x8_t;
typedef __attribute__((ext_vector_type(4))) float f32x4_t;

__device__ __forceinline__ unsigned short f2bf(float f) {
    unsigned u = __float_as_uint(f);
    u += 0x7FFFu + ((u >> 16) & 1u);   // RNE
    return (unsigned short)(u >> 16);
}

// ---------------- GroupNorm stats: one block per (b,g); group data is contiguous ----------------
__global__ __launch_bounds__(256) void gn_stats_k(const float* __restrict__ x,
                                                  float* __restrict__ stats) {
    int bg = blockIdx.x;  // 0..31
    const float4* base = (const float4*)(x + (size_t)bg * CPG * HW);
    const int n4 = CPG * HW / 4;  // 32768
    float s = 0.f, ss = 0.f;
    for (int i = threadIdx.x; i < n4; i += 256) {
        float4 v = base[i];
        s  += v.x + v.y + v.z + v.w;
        ss += v.x*v.x + v.y*v.y + v.z*v.z + v.w*v.w;
    }
    #pragma unroll
    for (int off = 32; off > 0; off >>= 1) {
        s  += __shfl_down(s, off);
        ss += __shfl_down(ss, off);
    }
    __shared__ float rs[4], rss[4];
    int wv = threadIdx.x >> 6;
    if ((threadIdx.x & 63) == 0) { rs[wv] = s; rss[wv] = ss; }
    __syncthreads();
    if (threadIdx.x == 0) {
        float S  = rs[0] + rs[1] + rs[2] + rs[3];
        float SS = rss[0] + rss[1] + rss[2] + rss[3];
        const float inv = 1.f / (float)(CPG * HW);
        float mean = S * inv;
        float var  = SS * inv - mean * mean;
        stats[2*bg]   = mean;
        stats[2*bg+1] = rsqrtf(var + EPS);
    }
}

// ---------------- GroupNorm apply (elementwise, float4) ----------------
__global__ __launch_bounds__(256) void gn_apply_k(const float* __restrict__ x,
                                                  const float* __restrict__ gamma,
                                                  const float* __restrict__ beta,
                                                  const float* __restrict__ stats,
                                                  float* __restrict__ h) {
    int idx = blockIdx.x * 256 + threadIdx.x;     // float4 index
    int bc = idx / (HW / 4);                       // b*256+c
    int b = bc >> 8, c = bc & 255;
    int bg = b * NG + (c >> 5);
    float mean = stats[2*bg], rstd = stats[2*bg+1];
    float sc = gamma[c] * rstd;
    float sh = beta[c] - mean * sc;
    float4 v = ((const float4*)x)[idx];
    float4 o;
    o.x = v.x*sc + sh; o.y = v.y*sc + sh; o.z = v.z*sc + sh; o.w = v.w*sc + sh;
    ((float4*)h)[idx] = o;
}

// ---------------- fp32 GEMM (used for proj): out[b][m][p] = A[m][:]·Bm[b][:][p] + bias[m] (+resid) ----------------
__global__ __launch_bounds__(256) void gemm_k(const float* __restrict__ A,
                                              const float* __restrict__ Bm,
                                              const float* __restrict__ bias,
                                              const float* __restrict__ resid,
                                              float* __restrict__ out,
                                              int Mdim) {
    __shared__ float Ast[16][68];
    __shared__ float Bs[16][68];
    int b  = blockIdx.z;
    int my = blockIdx.y;
    int nx = blockIdx.x;
    int t = threadIdx.x;
    int ty = t >> 4, tx = t & 15;
    const float* Ab = A + (size_t)my * 64 * 256;
    const float* Bb = Bm + (size_t)b * 256 * HW + nx * 64;
    float acc[4][4] = {};
    int lr  = t >> 2;
    int lc  = (t & 3) * 4;
    int brr = t >> 4;
    int bc4 = (t & 15) * 4;
    for (int k0 = 0; k0 < 256; k0 += 16) {
        float4 av = *(const float4*)(Ab + lr * 256 + k0 + lc);
        float4 bv = *(const float4*)(Bb + (size_t)(k0 + brr) * HW + bc4);
        Ast[lc + 0][lr] = av.x;
        Ast[lc + 1][lr] = av.y;
        Ast[lc + 2][lr] = av.z;
        Ast[lc + 3][lr] = av.w;
        *(float4*)&Bs[brr][bc4] = bv;
        __syncthreads();
        #pragma unroll
        for (int kk = 0; kk < 16; kk++) {
            float4 a4 = *(const float4*)&Ast[kk][ty * 4];
            float4 b4 = *(const float4*)&Bs[kk][tx * 4];
            acc[0][0] += a4.x*b4.x; acc[0][1] += a4.x*b4.y; acc[0][2] += a4.x*b4.z; acc[0][3] += a4.x*b4.w;
            acc[1][0] += a4.y*b4.x; acc[1][1] += a4.y*b4.y; acc[1][2] += a4.y*b4.z; acc[1][3] += a4.y*b4.w;
            acc[2][0] += a4.z*b4.x; acc[2][1] += a4.z*b4.y; acc[2][2] += a4.z*b4.z; acc[2][3] += a4.z*b4.w;
            acc[3][0] += a4.w*b4.x; acc[3][1] += a4.w*b4.y; acc[3][2] += a4.w*b4.z; acc[3][3] += a4.w*b4.w;
        }
        __syncthreads();
    }
    #pragma unroll
    for (int r = 0; r < 4; r++) {
        int m = my * 64 + ty * 4 + r;
        size_t off = ((size_t)b * Mdim + m) * HW + nx * 64 + tx * 4;
        float bsv = bias[m];
        float4 o;
        o.x = acc[r][0] + bsv; o.y = acc[r][1] + bsv; o.z = acc[r][2] + bsv; o.w = acc[r][3] + bsv;
        if (resid != nullptr) {
            float4 rv = *(const float4*)(resid + off);
            o.x += rv.x; o.y += rv.y; o.z += rv.z; o.w += rv.w;
        }
        *(float4*)(out + off) = o;
    }
}

// ---------------- QKV GEMM (fp32 math) with bf16 multi-layout epilogue ----------------
// my 0..3: Q head my  -> qt[(b,h)][p][d] bf16, scaled by QSCALE (transposed via LDS)
// my 4..7: K head my-4-> kt[(b,h)][p][d] bf16 (transposed via LDS)
// my 8..11:V head my-8-> vv[(b,h)][d][p] bf16 (direct)
__global__ __launch_bounds__(256) void gemm_qkv_k(const float* __restrict__ A,     // w_qkv [768][256]
                                                  const float* __restrict__ Bm,    // h [NB][256][HW]
                                                  const float* __restrict__ bias,  // [768]
                                                  unsigned short* __restrict__ qt,
                                                  unsigned short* __restrict__ kt,
                                                  unsigned short* __restrict__ vv) {
    __shared__ float Ast[16][68];
    __shared__ float Bs[16][68];
    __shared__ unsigned short T[64][72];   // [p][d] staging, 144B rows (16B aligned)
    int b  = blockIdx.z;
    int my = blockIdx.y;   // 0..11
    int nx = blockIdx.x;
    int t = threadIdx.x;
    int ty = t >> 4, tx = t & 15;
    const float* Ab = A + (size_t)my * 64 * 256;
    const float* Bb = Bm + (size_t)b * 256 * HW + nx * 64;
    float acc[4][4] = {};
    int lr  = t >> 2;
    int lc  = (t & 3) * 4;
    int brr = t >> 4;
    int bc4 = (t & 15) * 4;
    for (int k0 = 0; k0 < 256; k0 += 16) {
        float4 av = *(const float4*)(Ab + lr * 256 + k0 + lc);
        float4 bv = *(const float4*)(Bb + (size_t)(k0 + brr) * HW + bc4);
        Ast[lc + 0][lr] = av.x;
        Ast[lc + 1][lr] = av.y;
        Ast[lc + 2][lr] = av.z;
        Ast[lc + 3][lr] = av.w;
        *(float4*)&Bs[brr][bc4] = bv;
        __syncthreads();
        #pragma unroll
        for (int kk = 0; kk < 16; kk++) {
            float4 a4 = *(const float4*)&Ast[kk][ty * 4];
            float4 b4 = *(const float4*)&Bs[kk][tx * 4];
            acc[0][0] += a4.x*b4.x; acc[0][1] += a4.x*b4.y; acc[0][2] += a4.x*b4.z; acc[0][3] += a4.x*b4.w;
            acc[1][0] += a4.y*b4.x; acc[1][1] += a4.y*b4.y; acc[1][2] += a4.y*b4.z; acc[1][3] += a4.y*b4.w;
            acc[2][0] += a4.z*b4.x; acc[2][1] += a4.z*b4.y; acc[2][2] += a4.z*b4.z; acc[2][3] += a4.z*b4.w;
            acc[3][0] += a4.w*b4.x; acc[3][1] += a4.w*b4.y; acc[3][2] += a4.w*b4.z; acc[3][3] += a4.w*b4.w;
        }
        __syncthreads();
    }
    int sec = my >> 2;        // 0=q, 1=k, 2=v
    int hh  = my & 3;
    if (sec == 2) {
        // V: direct [d][p] bf16 store
        #pragma unroll
        for (int r = 0; r < 4; r++) {
            int d = ty * 4 + r;
            float bsv = bias[my * 64 + d];
            size_t off = ((size_t)(b * NH + hh) * 64 + d) * HW + nx * 64 + tx * 4;
            ushort4 o;
            o.x = f2bf(acc[r][0] + bsv); o.y = f2bf(acc[r][1] + bsv);
            o.z = f2bf(acc[r][2] + bsv); o.w = f2bf(acc[r][3] + bsv);
            *(ushort4*)(vv + off) = o;
        }
    } else {
        // Q/K: transpose through LDS -> [p][d] bf16
        float sc = (sec == 0) ? QSCALE : 1.f;
        #pragma unroll
        for (int r = 0; r < 4; r++) {
            float bsv = bias[my * 64 + ty * 4 + r];
            #pragma unroll
            for (int c = 0; c < 4; c++)
                T[tx * 4 + c][ty * 4 + r] = f2bf((acc[r][c] + bsv) * sc);
        }
        __syncthreads();
        unsigned short* dst = ((sec == 0) ? qt : kt) + ((size_t)(b * NH + hh) * HW + nx * 64) * 64;
        int p = t >> 2, cc = t & 3;
        *(uint4*)(dst + p * 64 + cc * 16)     = *(const uint4*)&T[p][cc * 16];
        *(uint4*)(dst + p * 64 + cc * 16 + 8) = *(const uint4*)&T[p][cc * 16 + 8];
    }
}

// ---------------- Flash attention, bf16 MFMA, i×j wave split ----------------
// qt,kt: [(b,h)][p][64] bf16 (Q pre-scaled by QSCALE); vv: [(b,h)][64][p] bf16.
// Block: 64-query tile, 4 waves = 2 i-halves (iw) x 2 j-halves (jw). Each wave handles
// 32 i x 32 j of every 64-j tile with its OWN online-softmax state (m,l per j-half);
// the two j-halves are merged once in the epilogue (split-k flash rescale).
// Grid 1024 -> 4 blocks/CU, 16 waves/CU (vs 8 in the 32i-per-wave version): 2x TLP
// to hide the per-iter chain; per-wave LDS reads drop to 12KB/iter.
// S^T = K·Q^T orientation (softmax per-lane-replicated, 2 shuffles per reduce).
__global__ __launch_bounds__(256, 4) void attn_k(const unsigned short* __restrict__ qt,
                                                 const unsigned short* __restrict__ kt,
                                                 const unsigned short* __restrict__ vv,
                                                 float* __restrict__ attno) {
    __shared__ __align__(16) unsigned short smem[12288];  // 24KB: K | V | P
    unsigned short* Klds = smem;          // 64 rows(j) x 64(d), swizzled 16B chunks
    unsigned short* Vlds = smem + 4096;   // 64 rows(d) x 64(j), swizzled
    unsigned short* Pt   = smem + 8192;   // [wave][mi][chunk 0..63][8] fragment-ready, 8KB
    int t = threadIdx.x;
    int wave = t >> 6, lane = t & 63, quad = lane >> 4, l16 = lane & 15;
    int iw = wave & 1, jw = wave >> 1;
    int i0 = blockIdx.x * 64;
    int hh = blockIdx.y, b = blockIdx.z;
    const unsigned short* qb  = qt + (size_t)(b * NH + hh) * HW * 64;
    const unsigned short* kbp = kt + (size_t)(b * NH + hh) * HW * 64;
    const unsigned short* vbp = vv + (size_t)(b * NH + hh) * 64 * HW;

    // Q B-frags: lane holds Q[i = i0+iw*32+mi*16+l16][d = kc*32+quad*8 ..+8]
    bf16x8_t qf[2][2];
    #pragma unroll
    for (int mi = 0; mi < 2; mi++)
        #pragma unroll
        for (int kc = 0; kc < 2; kc++)
            qf[mi][kc] = *(const bf16x8_t*)(qb + (size_t)(i0 + iw * 32 + mi * 16 + l16) * 64 + kc * 32 + quad * 8);

    f32x4_t oacc[4][2];
    const f32x4_t zz = {0.f, 0.f, 0.f, 0.f};
    #pragma unroll
    for (int dt = 0; dt < 4; dt++) { oacc[dt][0] = zz; oacc[dt][1] = zz; }
    float m_pr[2] = {-INFINITY, -INFINITY};
    float l_sum[2] = {0.f, 0.f};

    // staging maps (constant per thread)
    int soffK[2], soffV[2], slds[2];
    #pragma unroll
    for (int n = 0; n < 2; n++) {
        int s = n * 256 + t;
        int row = s >> 3;
        int c = (s & 7) ^ (row & 7);
        soffK[n] = row * 128 + c * 16;          // bytes (row=j, 128B rows)
        soffV[n] = row * (HW * 2) + c * 16;     // bytes (row=d, stride HW*2)
        slds[n] = s * 8;                        // ushort index
    }
    uint4 kreg[2], vreg[2];
    {
        const char* kbase = (const char*)kbp;
        const char* vbase = (const char*)vbp;
        kreg[0] = *(const uint4*)(kbase + soffK[0]); kreg[1] = *(const uint4*)(kbase + soffK[1]);
        vreg[0] = *(const uint4*)(vbase + soffV[0]); vreg[1] = *(const uint4*)(vbase + soffV[1]);
    }

    for (int jt = 0; jt < 64; jt++) {
        __syncthreads();   // previous tile fully consumed
        *(uint4*)&Klds[slds[0]] = kreg[0]; *(uint4*)&Klds[slds[1]] = kreg[1];
        *(uint4*)&Vlds[slds[0]] = vreg[0]; *(uint4*)&Vlds[slds[1]] = vreg[1];
        __syncthreads();   // tiles ready
        if (jt < 63) {     // prefetch next tile into regs
            const char* kbase = (const char*)kbp + (size_t)(jt + 1) * 8192;
            const char* vbase = (const char*)vbp + (size_t)(jt + 1) * 128;
            kreg[0] = *(const uint4*)(kbase + soffK[0]); kreg[1] = *(const uint4*)(kbase + soffK[1]);
            vreg[0] = *(const uint4*)(vbase + soffV[0]); vreg[1] = *(const uint4*)(vbase + soffV[1]);
        }

        // ---- S^T = K·Q^T on this wave's 32 j x 32 i ----
        f32x4_t sacc[2][2];
        sacc[0][0] = zz; sacc[0][1] = zz; sacc[1][0] = zz; sacc[1][1] = zz;
        #pragma unroll
        for (int nj = 0; nj < 2; nj++) {
            int j = jw * 32 + nj * 16 + l16;        // A-operand row
            int rb = j * 8;
            bf16x8_t kf0 = *(const bf16x8_t*)&Klds[(rb + ((quad    ) ^ (j & 7))) * 8];
            bf16x8_t kf1 = *(const bf16x8_t*)&Klds[(rb + ((4 + quad) ^ (j & 7))) * 8];
            #pragma unroll
            for (int mi = 0; mi < 2; mi++) {
                sacc[mi][nj] = __builtin_amdgcn_mfma_f32_16x16x32_bf16(kf0, qf[mi][0], sacc[mi][nj], 0, 0, 0);
                sacc[mi][nj] = __builtin_amdgcn_mfma_f32_16x16x32_bf16(kf1, qf[mi][1], sacc[mi][nj], 0, 0, 0);
            }
        }

        // ---- online softmax (base-2) per i-tile; state per-lane-replicated, j-half-local ----
        float alpha_[2];
        #pragma unroll
        for (int mi = 0; mi < 2; mi++) {
            float m = sacc[mi][0][0];
            #pragma unroll
            for (int nj = 0; nj < 2; nj++)
                #pragma unroll
                for (int r = 0; r < 4; r++) m = fmaxf(m, sacc[mi][nj][r]);
            m = fmaxf(m, __shfl_xor(m, 16));
            m = fmaxf(m, __shfl_xor(m, 32));
            float mnew = fmaxf(m_pr[mi], m);
            float a = __builtin_amdgcn_exp2f(m_pr[mi] - mnew);
            alpha_[mi] = a;
            float rs = 0.f;
            #pragma unroll
            for (int nj = 0; nj < 2; nj++)
                #pragma unroll
                for (int r = 0; r < 4; r++) {
                    float p = __builtin_amdgcn_exp2f(sacc[mi][nj][r] - mnew);
                    sacc[mi][nj][r] = p;
                    rs += p;
                }
            rs += __shfl_xor(rs, 16);
            rs += __shfl_xor(rs, 32);
            l_sum[mi] = l_sum[mi] * a + rs;
            m_pr[mi] = mnew;

            // P -> wave-private LDS, fragment-ready: writer (quad,l16) holds
            // P[j' = nj*16+quad*4+r][i' = mi*16+l16]; reader chunk = rq*16+l16 with
            // j' = rq*8+idx  =>  rq = nj*2+(quad>>1), halfword off 4*(quad&1).
            #pragma unroll
            for (int nj = 0; nj < 2; nj++) {
                unsigned lo = (unsigned)f2bf(sacc[mi][nj][0]) | ((unsigned)f2bf(sacc[mi][nj][1]) << 16);
                unsigned hi = (unsigned)f2bf(sacc[mi][nj][2]) | ((unsigned)f2bf(sacc[mi][nj][3]) << 16);
                int chunk = (nj * 2 + (quad >> 1)) * 16 + l16;
                *(uint2*)&Pt[((wave * 2 + mi) * 64 + chunk) * 8 + 4 * (quad & 1)] = make_uint2(lo, hi);
            }
        }

        // rescale O by alpha (registers only)
        #pragma unroll
        for (int dt = 0; dt < 4; dt++) { oacc[dt][0] *= alpha_[0]; oacc[dt][1] *= alpha_[1]; }

        __threadfence_block();   // wave-private P round-trip: fence compiler + lgkm (r2 lesson)

        // ---- PV: O^T[d][i] += V[d][j-half]·P[j-half][i], K-dim = this wave's 32 j ----
        bf16x8_t pf[2];
        pf[0] = *(const bf16x8_t*)&Pt[((wave * 2 + 0) * 64 + quad * 16 + l16) * 8];
        pf[1] = *(const bf16x8_t*)&Pt[((wave * 2 + 1) * 64 + quad * 16 + l16) * 8];
        #pragma unroll
        for (int dt = 0; dt < 4; dt++) {
            int d = dt * 16 + l16;
            bf16x8_t vf = *(const bf16x8_t*)&Vlds[(d * 8 + ((jw * 4 + quad) ^ (d & 7))) * 8];
            oacc[dt][0] = __builtin_amdgcn_mfma_f32_16x16x32_bf16(vf, pf[0], oacc[dt][0], 0, 0, 0);
            oacc[dt][1] = __builtin_amdgcn_mfma_f32_16x16x32_bf16(vf, pf[1], oacc[dt][1], 0, 0, 0);
        }
    }

    // ---- epilogue: merge the two j-halves (split-k flash rescale), write O^T fp32 ----
    __syncthreads();                       // all K/V/P consumption done; reuse smem
    float* Obuf = (float*)smem;            // [iw][64 d][32 i'] = 16KB
    float2* ml  = (float2*)Pt;             // [iw][32 i'] (m, l)
    if (jw == 0) {
        #pragma unroll
        for (int dt = 0; dt < 4; dt++)
            #pragma unroll
            for (int mi = 0; mi < 2; mi++)
                #pragma unroll
                for (int r = 0; r < 4; r++)
                    Obuf[iw * 2048 + (dt * 16 + quad * 4 + r) * 32 + mi * 16 + l16] = oacc[dt][mi][r];
        if (quad == 0) {
            ml[iw * 32 + l16]      = make_float2(m_pr[0], l_sum[0]);
            ml[iw * 32 + 16 + l16] = make_float2(m_pr[1], l_sum[1]);
        }
    }
    __syncthreads();
    if (jw == 1) {
        float c0[2], c1[2];
        #pragma unroll
        for (int mi = 0; mi < 2; mi++) {
            float2 s0 = ml[iw * 32 + mi * 16 + l16];
            float mm = fmaxf(s0.x, m_pr[mi]);
            float a0 = __builtin_amdgcn_exp2f(s0.x - mm);
            float a1 = __builtin_amdgcn_exp2f(m_pr[mi] - mm);
            float l  = s0.y * a0 + l_sum[mi] * a1;
            c0[mi] = a0 / l; c1[mi] = a1 / l;
        }
        float* ob = attno + (size_t)(b * NH + hh) * 64 * HW + i0 + iw * 32;
        #pragma unroll
        for (int dt = 0; dt < 4; dt++)
            #pragma unroll
            for (int mi = 0; mi < 2; mi++)
                #pragma unroll
                for (int r = 0; r < 4; r++) {
                    int d = dt * 16 + quad * 4 + r;
                    float v = Obuf[iw * 2048 + d * 32 + mi * 16 + l16] * c0[mi] + oacc[dt][mi][r] * c1[mi];
                    ob[(size_t)d * HW + mi * 16 + l16] = v;
                }
    }
}

extern "C" void kernel_launch(void* const* d_in, const int* in_sizes, int n_in,
                              void* d_out, int out_size, void* d_ws, size_t ws_size,
                              hipStream_t stream) {
    const float* x      = (const float*)d_in[0];
    const float* gamma  = (const float*)d_in[1];
    const float* beta   = (const float*)d_in[2];
    const float* w_qkv  = (const float*)d_in[3];
    const float* b_qkv  = (const float*)d_in[4];
    const float* w_proj = (const float*)d_in[5];
    const float* b_proj = (const float*)d_in[6];
    float* out = (float*)d_out;

    // ws: stats[256] | attno fp32 [4M] | qt bf16 [4M] | kt bf16 [4M] | vv bf16 [4M]  => ~41 MB
    float* stats = (float*)d_ws;
    float* attno = stats + 256;
    unsigned short* qt = (unsigned short*)(attno + (size_t)NB * C_ * HW);
    unsigned short* kt = qt + (size_t)NB * NH * HW * 64;
    unsigned short* vv = kt + (size_t)NB * NH * HW * 64;
    float* h = out;  // reuse d_out as GroupNorm output; consumed by gemm_qkv, overwritten by final GEMM

    gn_stats_k<<<32, 256, 0, stream>>>(x, stats);
    gn_apply_k<<<NB * C_ * HW / 4 / 256, 256, 0, stream>>>(x, gamma, beta, stats, h);
    gemm_qkv_k<<<dim3(HW / 64, 12, NB), 256, 0, stream>>>(w_qkv, h, b_qkv, qt, kt, vv);
    attn_k<<<dim3(HW / 64, NH, NB), 256, 0, stream>>>(qt, kt, vv, attno);
    gemm_k<<<dim3(HW / 64, 4, NB), 256, 0, stream>>>(w_proj, attno, b_proj, x, out, 256);
}